// Round 14
// baseline (95.307 us; speedup 1.0000x reference)
//
#include <hip/hip_runtime.h>

#define NB 512
#define SLOTS 32
#define D 1024
#define D4 256           // D/4 (float4 per row)
#define TC 4             // tokens per chunk (per quarter)
#define CAP 64           // list capacity per bucket
#define TAU_INV 10.0f
#define BT 256           // threads per block (4 waves)

// ---- kernel 0: zero the per-bucket counters ----
__global__ void k_zero(int* __restrict__ cnt) {
    if (threadIdx.x < NB) cnt[threadIdx.x] = 0;
}

// ---- kernel 1: build per-bucket token lists (order nondeterministic, but
//      per-token math is order-invariant → deterministic output) ----
__global__ void k_build(const int* __restrict__ tids, int n,
                        int* __restrict__ cnt, int* __restrict__ list) {
    int i = blockIdx.x * 256 + threadIdx.x;
    if (i < n) {
        int b = tids[i] & (NB - 1);
        int p = atomicAdd(&cnt[b], 1);
        if (p < CAP) list[b * CAP + p] = i;
    }
}

// ---- kernel 2: quarter-split buckets, TC=4, fused softmax+value.
//      grid = 4*NB; block = (bucket = bid&511, q = bid>>9) owns positions
//      q, q+4, ... (all 4 quarters of a bucket share an XCD: 512%8==0).
//      LDS ~16.5 KB -> 8 blocks/CU -> 32 waves/CU static (R11 was 16).
//      2 barriers/chunk: query -> bar -> scores -> bar -> softmax+value
//      fused per wave (weights via shfl, no s_probs round-trip).
__global__ __launch_bounds__(BT, 2)
void k_main(const float* __restrict__ query,    // [NT][D]
            const int*   __restrict__ tids,     // [NT]
            const float* __restrict__ skeys,    // [NB*SLOTS][D]
            const float* __restrict__ svals,    // [NB*SLOTS][D]
            const int*   __restrict__ stids,    // [NB*SLOTS]
            const float* __restrict__ centroid, // [NB][D]
            float*       __restrict__ out,      // [NT][D]
            const int*   __restrict__ cnt,
            const int*   __restrict__ list)
{
    const int bucket = blockIdx.x & (NB - 1);
    const int q      = blockIdx.x >> 9;         // 0..3
    const int tidx   = threadIdx.x;             // 0..255
    const int lane   = tidx & 63;
    const int wid    = tidx >> 6;               // 0..3
    const int ls     = lane & 31;

    const int count = min(cnt[bucket], CAP);
    const int ncnt  = (count - q + 3) >> 2;     // positions q, q+4, ...
    if (ncnt <= 0) return;

    __shared__ float s_uq[TC][D];               // 16 KB
    __shared__ float s_scores[TC][SLOTS];       // 512 B

    const int slot_tid = stids[bucket * SLOTS + ls];
    const float4* kb = (const float4*)(skeys + (size_t)bucket * SLOTS * D);
    const float4* vb = (const float4*)(svals + (size_t)bucket * SLOTS * D);
    const float4* cb = (const float4*)(centroid + (size_t)bucket * D);

    for (int c0 = 0; c0 < ncnt; c0 += TC) {
        const int nt = min(TC, ncnt - c0);

        int tok = -1, my_tid = 0;
        // ---- query phase: wave w owns token w (1 round; regs + LDS write) ----
        if (wid < nt) {
            tok = list[bucket * CAP + q + 4 * (c0 + wid)];
            my_tid = tids[tok];
            const float4* q4 = (const float4*)(query + (size_t)tok * D);
            float4 qv[4], anc[4];
            float ss = 0.f;
            #pragma unroll
            for (int j = 0; j < 4; ++j) {
                qv[j]  = q4[lane + 64 * j];
                anc[j] = cb[lane + 64 * j];
                ss += qv[j].x*qv[j].x + qv[j].y*qv[j].y + qv[j].z*qv[j].z + qv[j].w*qv[j].w;
            }
            #pragma unroll
            for (int off = 32; off >= 1; off >>= 1) ss += __shfl_xor(ss, off);
            const float qn = 0.5f / fmaxf(sqrtf(ss), 1e-12f);   // folds ALPHA=0.5
            float4 uv[4];
            float ss2 = 0.f;
            #pragma unroll
            for (int j = 0; j < 4; ++j) {
                uv[j].x = qv[j].x * qn + 0.5f * anc[j].x;
                uv[j].y = qv[j].y * qn + 0.5f * anc[j].y;
                uv[j].z = qv[j].z * qn + 0.5f * anc[j].z;
                uv[j].w = qv[j].w * qn + 0.5f * anc[j].w;
                ss2 += uv[j].x*uv[j].x + uv[j].y*uv[j].y + uv[j].z*uv[j].z + uv[j].w*uv[j].w;
            }
            #pragma unroll
            for (int off = 32; off >= 1; off >>= 1) ss2 += __shfl_xor(ss2, off);
            const float un = 1.0f / fmaxf(sqrtf(ss2), 1e-12f);
            #pragma unroll
            for (int j = 0; j < 4; ++j) {
                ((float4*)s_uq[wid])[lane + 64 * j] =
                    make_float4(uv[j].x*un, uv[j].y*un, uv[j].z*un, uv[j].w*un);
            }
        }
        __syncthreads();   // barrier 1: s_uq visible

        // ---- scores: 2 rounds; wave owns 4 slots/round (R11 shape, 60 VGPR) ----
        #pragma unroll 1
        for (int rnd = 0; rnd < 2; ++rnd) {
            const int sbase = rnd * 16 + wid * 4;
            const float4* kr = kb + (size_t)sbase * D4;
            float4 k0[4], k1[4], k2[4], k3[4];
            #pragma unroll
            for (int j = 0; j < 4; ++j) {
                k0[j] = kr[0 * D4 + lane + 64 * j];
                k1[j] = kr[1 * D4 + lane + 64 * j];
                k2[j] = kr[2 * D4 + lane + 64 * j];
                k3[j] = kr[3 * D4 + lane + 64 * j];
            }
            for (int t = 0; t < nt; ++t) {          // runtime bound: anti-spill
                const float4* u4 = (const float4*)s_uq[t];
                float P0 = 0.f, P1 = 0.f, P2 = 0.f, P3 = 0.f;
                #pragma unroll
                for (int j = 0; j < 4; ++j) {
                    float4 u = u4[lane + 64 * j];
                    P0 += k0[j].x*u.x + k0[j].y*u.y + k0[j].z*u.z + k0[j].w*u.w;
                    P1 += k1[j].x*u.x + k1[j].y*u.y + k1[j].z*u.z + k1[j].w*u.w;
                    P2 += k2[j].x*u.x + k2[j].y*u.y + k2[j].z*u.z + k2[j].w*u.w;
                    P3 += k3[j].x*u.x + k3[j].y*u.y + k3[j].z*u.z + k3[j].w*u.w;
                }
                // batched paired-halving reduce: 4 values, 7 shfl (R10-verified)
                {
                    const bool hi = (lane & 1) != 0;
                    const float sA = hi ? P0 : P2, kA = hi ? P2 : P0;
                    P0 = kA + __shfl_xor(sA, 1);
                    const float sB = hi ? P1 : P3, kB = hi ? P3 : P1;
                    P1 = kB + __shfl_xor(sB, 1);
                }
                {
                    const bool hi = (lane & 2) != 0;
                    const float sA = hi ? P0 : P1, kA = hi ? P1 : P0;
                    P0 = kA + __shfl_xor(sA, 2);
                }
                P0 += __shfl_xor(P0, 4);
                P0 += __shfl_xor(P0, 8);
                P0 += __shfl_xor(P0, 16);
                P0 += __shfl_xor(P0, 32);
                // lane l<4 holds slot id = ((l&1)<<1)|((l>>1)&1)
                if (lane < 4)
                    s_scores[t][sbase + (((lane & 1) << 1) | ((lane >> 1) & 1))] = P0;
            }
        }
        __syncthreads();   // barrier 2: s_scores visible

        // ---- fused softmax + value: wave w owns token w end-to-end ----
        if (wid < nt) {
            // softmax + hard-match, computed in all 64 lanes (dup halves)
            const float sc = s_scores[wid][ls];
            float mx = sc;
            #pragma unroll
            for (int off = 16; off >= 1; off >>= 1) mx = fmaxf(mx, __shfl_xor(mx, off));
            const float e = __expf((sc - mx) * TAU_INV);
            const float f = (slot_tid == my_tid) ? 1.f : 0.f;
            float es = e, ms = f;
            #pragma unroll
            for (int off = 16; off >= 1; off >>= 1) {
                es += __shfl_xor(es, off);
                ms += __shfl_xor(ms, off);
            }
            const float p = (ms > 0.f) ? f / (ms + 1e-9f) : e / es;
            // weight of slot s lives in lane s (0..31): shfl broadcast

            float4 acc[4];
            #pragma unroll
            for (int j = 0; j < 4; ++j) acc[j] = make_float4(0.f, 0.f, 0.f, 0.f);
            #pragma unroll 1
            for (int g = 0; g < 8; ++g) {
                const float4* vr = vb + (size_t)(g * 4) * D4;
                float4 r0[4], r1[4], r2[4], r3[4];
                #pragma unroll
                for (int j = 0; j < 4; ++j) {
                    r0[j] = vr[0 * D4 + lane + 64 * j];
                    r1[j] = vr[1 * D4 + lane + 64 * j];
                    r2[j] = vr[2 * D4 + lane + 64 * j];
                    r3[j] = vr[3 * D4 + lane + 64 * j];
                }
                const float w0 = __shfl(p, g * 4 + 0);
                const float w1 = __shfl(p, g * 4 + 1);
                const float w2 = __shfl(p, g * 4 + 2);
                const float w3 = __shfl(p, g * 4 + 3);
                #pragma unroll
                for (int j = 0; j < 4; ++j) {
                    acc[j].x += w0*r0[j].x + w1*r1[j].x + w2*r2[j].x + w3*r3[j].x;
                    acc[j].y += w0*r0[j].y + w1*r1[j].y + w2*r2[j].y + w3*r3[j].y;
                    acc[j].z += w0*r0[j].z + w1*r1[j].z + w2*r2[j].z + w3*r3[j].z;
                    acc[j].w += w0*r0[j].w + w1*r1[j].w + w2*r2[j].w + w3*r3[j].w;
                }
            }
            float4* o4 = (float4*)(out + (size_t)tok * D);
            #pragma unroll
            for (int j = 0; j < 4; ++j) o4[lane + 64 * j] = acc[j];
        }
        if (c0 + TC < ncnt) __syncthreads();   // only multi-chunk blocks
    }
}

extern "C" void kernel_launch(void* const* d_in, const int* in_sizes, int n_in,
                              void* d_out, int out_size, void* d_ws, size_t ws_size,
                              hipStream_t stream) {
    const float* query    = (const float*)d_in[0];
    const int*   tids     = (const int*)  d_in[1];
    const float* skeys    = (const float*)d_in[2];
    const float* svals    = (const float*)d_in[3];
    const int*   stids    = (const int*)  d_in[4];
    const float* centroid = (const float*)d_in[5];
    float* out = (float*)d_out;
    const int n_tokens = in_sizes[1];

    int* cnt  = (int*)d_ws;             // [NB]
    int* list = cnt + NB;               // [NB*CAP]

    k_zero<<<1, 512, 0, stream>>>(cnt);
    k_build<<<(n_tokens + 255) / 256, 256, 0, stream>>>(tids, n_tokens, cnt, list);
    k_main<<<NB * 4, BT, 0, stream>>>(query, tids, skeys, svals, stids,
                                      centroid, out, cnt, list);
}

// Round 15
// 65.374 us; speedup vs baseline: 1.4579x; 1.4579x over previous
//
#include <hip/hip_runtime.h>

#define NB 512
#define SLOTS 32
#define D 1024
#define D4 256           // D/4 (float4 per row)
#define TC 8             // tokens per chunk (per part)
#define CAP 64           // list capacity per bucket
#define TAU_INV 10.0f
#define BT 512           // threads per block (8 waves)

// ---- kernel 0: zero the per-bucket counters ----
__global__ void k_zero(int* __restrict__ cnt) {
    if (threadIdx.x < NB) cnt[threadIdx.x] = 0;
}

// ---- kernel 1: build per-bucket token lists (order nondeterministic, but
//      per-token math is order-invariant → deterministic output) ----
__global__ void k_build(const int* __restrict__ tids, int n,
                        int* __restrict__ cnt, int* __restrict__ list) {
    int i = blockIdx.x * 256 + threadIdx.x;
    if (i < n) {
        int b = tids[i] & (NB - 1);
        int p = atomicAdd(&cnt[b], 1);
        if (p < CAP) list[b * CAP + p] = i;
    }
}

// ---- kernel 2: R11 partition (2-way parity split, TC=8, ~35 KB LDS) but
//      8 WAVES per block: 4 blocks/CU x 8 waves = 32 waves/CU static (HW cap,
//      2x R11) with identical memory traffic. Every phase is 1 round:
//      query (wave w = token w), score (wave w = slots 4w..4w+3), value
//      (thread-group per token-half, vals re-read via L1 -> no LDS combine).
__global__ __launch_bounds__(BT, 2)
void k_main(const float* __restrict__ query,    // [NT][D]
            const int*   __restrict__ tids,     // [NT]
            const float* __restrict__ skeys,    // [NB*SLOTS][D]
            const float* __restrict__ svals,    // [NB*SLOTS][D]
            const int*   __restrict__ stids,    // [NB*SLOTS]
            const float* __restrict__ centroid, // [NB][D]
            float*       __restrict__ out,      // [NT][D]
            const int*   __restrict__ cnt,
            const int*   __restrict__ list)
{
    const int bucket = blockIdx.x & (NB - 1);   // parts share XCD (512%8==0)
    const int part   = blockIdx.x >> 9;         // 0/1
    const int tidx   = threadIdx.x;             // 0..511
    const int lane   = tidx & 63;
    const int wid    = tidx >> 6;               // 0..7

    const int count = min(cnt[bucket], CAP);
    const int ncnt  = (count - part + 1) >> 1;  // tokens owned by this part
    if (ncnt <= 0) return;

    __shared__ float s_uq[TC][D];               // 32 KB
    __shared__ float s_scores[TC][SLOTS];       // 1 KB
    __shared__ float s_probs[TC][SLOTS];        // 1 KB
    __shared__ int   s_tok[TC];
    __shared__ int   s_ttid[TC];

    const int slot_tid = stids[bucket * SLOTS + (lane & 31)];
    const float4* kb = (const float4*)(skeys + (size_t)bucket * SLOTS * D);
    const float4* vb = (const float4*)(svals + (size_t)bucket * SLOTS * D);
    const float4* cb = (const float4*)(centroid + (size_t)bucket * D);

    for (int c0 = 0; c0 < ncnt; c0 += TC) {
        const int nt = min(TC, ncnt - c0);

        // ---- query phase: wave w owns token w (single round, 8 waves) ----
        if (wid < nt) {
            const int tok = list[bucket * CAP + part + 2 * (c0 + wid)];
            const float4* q4 = (const float4*)(query + (size_t)tok * D);
            float4 qv[4], anc[4];
            float ss = 0.f;
            #pragma unroll
            for (int j = 0; j < 4; ++j) {
                qv[j]  = q4[lane + 64 * j];
                anc[j] = cb[lane + 64 * j];
                ss += qv[j].x*qv[j].x + qv[j].y*qv[j].y + qv[j].z*qv[j].z + qv[j].w*qv[j].w;
            }
            #pragma unroll
            for (int off = 32; off >= 1; off >>= 1) ss += __shfl_xor(ss, off);
            const float qn = 0.5f / fmaxf(sqrtf(ss), 1e-12f);   // folds ALPHA=0.5
            float4 uv[4];
            float ss2 = 0.f;
            #pragma unroll
            for (int j = 0; j < 4; ++j) {
                uv[j].x = qv[j].x * qn + 0.5f * anc[j].x;
                uv[j].y = qv[j].y * qn + 0.5f * anc[j].y;
                uv[j].z = qv[j].z * qn + 0.5f * anc[j].z;
                uv[j].w = qv[j].w * qn + 0.5f * anc[j].w;
                ss2 += uv[j].x*uv[j].x + uv[j].y*uv[j].y + uv[j].z*uv[j].z + uv[j].w*uv[j].w;
            }
            #pragma unroll
            for (int off = 32; off >= 1; off >>= 1) ss2 += __shfl_xor(ss2, off);
            const float un = 1.0f / fmaxf(sqrtf(ss2), 1e-12f);
            #pragma unroll
            for (int j = 0; j < 4; ++j) {
                ((float4*)s_uq[wid])[lane + 64 * j] =
                    make_float4(uv[j].x*un, uv[j].y*un, uv[j].z*un, uv[j].w*un);
            }
            if (lane == 0) { s_tok[wid] = tok; s_ttid[wid] = tids[tok]; }
        }
        __syncthreads();   // barrier 1: s_uq visible

        // ---- scores: ONE round; wave owns slots [4w, 4w+4) (R11 body) ----
        {
            const int sbase = wid * 4;
            const float4* kr = kb + (size_t)sbase * D4;
            float4 k0[4], k1[4], k2[4], k3[4];
            #pragma unroll
            for (int j = 0; j < 4; ++j) {
                k0[j] = kr[0 * D4 + lane + 64 * j];
                k1[j] = kr[1 * D4 + lane + 64 * j];
                k2[j] = kr[2 * D4 + lane + 64 * j];
                k3[j] = kr[3 * D4 + lane + 64 * j];
            }
            for (int t = 0; t < nt; ++t) {          // runtime bound: anti-spill
                const float4* u4 = (const float4*)s_uq[t];
                float P0 = 0.f, P1 = 0.f, P2 = 0.f, P3 = 0.f;
                #pragma unroll
                for (int j = 0; j < 4; ++j) {
                    float4 u = u4[lane + 64 * j];
                    P0 += k0[j].x*u.x + k0[j].y*u.y + k0[j].z*u.z + k0[j].w*u.w;
                    P1 += k1[j].x*u.x + k1[j].y*u.y + k1[j].z*u.z + k1[j].w*u.w;
                    P2 += k2[j].x*u.x + k2[j].y*u.y + k2[j].z*u.z + k2[j].w*u.w;
                    P3 += k3[j].x*u.x + k3[j].y*u.y + k3[j].z*u.z + k3[j].w*u.w;
                }
                // batched paired-halving reduce: 4 values, 7 shfl (R10-verified)
                {
                    const bool hi = (lane & 1) != 0;
                    const float sA = hi ? P0 : P2, kA = hi ? P2 : P0;
                    P0 = kA + __shfl_xor(sA, 1);
                    const float sB = hi ? P1 : P3, kB = hi ? P3 : P1;
                    P1 = kB + __shfl_xor(sB, 1);
                }
                {
                    const bool hi = (lane & 2) != 0;
                    const float sA = hi ? P0 : P1, kA = hi ? P1 : P0;
                    P0 = kA + __shfl_xor(sA, 2);
                }
                P0 += __shfl_xor(P0, 4);
                P0 += __shfl_xor(P0, 8);
                P0 += __shfl_xor(P0, 16);
                P0 += __shfl_xor(P0, 32);
                // lane l<4 holds slot id = ((l&1)<<1)|((l>>1)&1)
                if (lane < 4)
                    s_scores[t][sbase + (((lane & 1) << 1) | ((lane >> 1) & 1))] = P0;
            }
        }
        __syncthreads();   // barrier 2: s_scores visible

        // ---- softmax + hard-match: wave w owns token w; lanes 0..31 ----
        if (wid < nt && lane < 32) {
            const float sc = s_scores[wid][lane];
            float mx = sc;
            #pragma unroll
            for (int off = 16; off >= 1; off >>= 1) mx = fmaxf(mx, __shfl_xor(mx, off));
            const float e = __expf((sc - mx) * TAU_INV);
            const float f = (slot_tid == s_ttid[wid]) ? 1.f : 0.f;
            float es = e, ms = f;
            #pragma unroll
            for (int off = 16; off >= 1; off >>= 1) {
                es += __shfl_xor(es, off);
                ms += __shfl_xor(ms, off);
            }
            s_probs[wid][lane] = (ms > 0.f) ? f / (ms + 1e-9f) : e / es;
        }
        __syncthreads();   // barrier 3: s_probs visible

        // ---- values: grp = tidx>>8 owns tokens [4g,4g+4); col = tidx&255.
        //      Both grps stream all 32 rows (2nd read is L1/L2-hot);
        //      no LDS combine, no extra barrier. 4 rounds of 8 loads. ----
        {
            const int col = tidx & 255;
            const int grp = tidx >> 8;
            float4 acc[4];
            #pragma unroll
            for (int k = 0; k < 4; ++k) acc[k] = make_float4(0.f, 0.f, 0.f, 0.f);

            #pragma unroll 1
            for (int s0 = 0; s0 < SLOTS; s0 += 8) {
                float4 v[8];
                #pragma unroll
                for (int i = 0; i < 8; ++i) v[i] = vb[(s0 + i) * D4 + col];
                #pragma unroll
                for (int k = 0; k < 4; ++k) {
                    const int t = grp * 4 + k;
                    if (t < nt) {
                        const float4 pA = ((const float4*)s_probs[t])[(s0 >> 2) + 0];
                        const float4 pB = ((const float4*)s_probs[t])[(s0 >> 2) + 1];
                        acc[k].x += pA.x*v[0].x + pA.y*v[1].x + pA.z*v[2].x + pA.w*v[3].x
                                  + pB.x*v[4].x + pB.y*v[5].x + pB.z*v[6].x + pB.w*v[7].x;
                        acc[k].y += pA.x*v[0].y + pA.y*v[1].y + pA.z*v[2].y + pA.w*v[3].y
                                  + pB.x*v[4].y + pB.y*v[5].y + pB.z*v[6].y + pB.w*v[7].y;
                        acc[k].z += pA.x*v[0].z + pA.y*v[1].z + pA.z*v[2].z + pA.w*v[3].z
                                  + pB.x*v[4].z + pB.y*v[5].z + pB.z*v[6].z + pB.w*v[7].z;
                        acc[k].w += pA.x*v[0].w + pA.y*v[1].w + pA.z*v[2].w + pA.w*v[3].w
                                  + pB.x*v[4].w + pB.y*v[5].w + pB.z*v[6].w + pB.w*v[7].w;
                    }
                }
            }
            #pragma unroll
            for (int k = 0; k < 4; ++k) {
                const int t = grp * 4 + k;
                if (t < nt) {
                    ((float4*)(out + (size_t)s_tok[t] * D))[col] = acc[k];
                }
            }
        }
        if (c0 + TC < ncnt) __syncthreads();   // only multi-chunk blocks
    }
}

extern "C" void kernel_launch(void* const* d_in, const int* in_sizes, int n_in,
                              void* d_out, int out_size, void* d_ws, size_t ws_size,
                              hipStream_t stream) {
    const float* query    = (const float*)d_in[0];
    const int*   tids     = (const int*)  d_in[1];
    const float* skeys    = (const float*)d_in[2];
    const float* svals    = (const float*)d_in[3];
    const int*   stids    = (const int*)  d_in[4];
    const float* centroid = (const float*)d_in[5];
    float* out = (float*)d_out;
    const int n_tokens = in_sizes[1];

    int* cnt  = (int*)d_ws;             // [NB]
    int* list = cnt + NB;               // [NB*CAP]

    k_zero<<<1, 512, 0, stream>>>(cnt);
    k_build<<<(n_tokens + 255) / 256, 256, 0, stream>>>(tids, n_tokens, cnt, list);
    k_main<<<NB * 2, BT, 0, stream>>>(query, tids, skeys, svals, stids,
                                      centroid, out, cnt, list);
}